// Round 3
// baseline (13852.321 us; speedup 1.0000x reference)
//
#include <hip/hip_runtime.h>

// BLSTM: B=128, S=512, H=1024, VOCAB=128.
//  k_init    : transpose x -> xT[t][b], zero barrier counters, pack h0 -> A-frag layout
//  k_zero    : zero the logits region of out (projection accumulates via atomicAdd)
//  k_gx      : Gx[dir][v][4096] = emb[v] @ W[:1024] + b   (fp32, one-time)
//  k_ubpack  : U = W[1024:2048] -> bf16 MFMA B-frag layout (register-resident in k_recur)
//  k_wobpack : W_out -> bf16 B-frag layout
//  k_recur   : persistent 256-block kernel (plain launch, 1 block/CU by VGPR pressure);
//              512 steps; 32-block group barrier/step. Recurrence (wave tile 32x32,
//              K=1024, B in 256 VGPRs) + fused projection (h staged in LDS reused as A;
//              cg<8 blocks atomicAdd 16 v-cols each into out). h ring 2-deep, 1MB.

#define B_ 128
#define S_ 512
#define H_ 1024
#define V_ 128

typedef float  f32x4  __attribute__((ext_vector_type(4)));
typedef __bf16 bf16x8 __attribute__((ext_vector_type(8)));

__device__ inline float sigm(float x)  { return 1.0f / (1.0f + __expf(-x)); }
__device__ inline float tanh_(float x) { return 2.0f / (1.0f + __expf(-2.0f * x)) - 1.0f; }

typedef __attribute__((address_space(1))) void gvoid_t;
typedef __attribute__((address_space(3))) void lvoid_t;

__device__ inline void gload_lds16(const void* g, void* l) {
  // async global->LDS, 16B/lane; LDS dst = wave-uniform base + lane*16
  __builtin_amdgcn_global_load_lds((gvoid_t*)g, (lvoid_t*)l, 16, 0, 0);
}

// ---------------------------------------------------------------------------
// k_init: xT + counters + h0 packed to A-frag layout (bf16)
// h0S: [dir][bt(8)][kk(32)][lane(64)][j(8)] bf16, elem = h[bt*16+(lane&15)][kk*32+(lane>>4)*8+j]
__global__ void k_init(const int* __restrict__ x, const float* __restrict__ h_f,
                       const float* __restrict__ h_b, int* __restrict__ xT,
                       unsigned short* __restrict__ h0S, unsigned* __restrict__ cnt) {
  int id = blockIdx.x * 256 + threadIdx.x;
  if (id < 65536) {
    int t = id >> 7, b = id & 127;
    xT[id] = x[b * S_ + t];
    if (id < 64) cnt[id] = 0u;
  } else {
    int i2 = id - 65536;            // 0..65535, 4 elems each
    int e0 = i2 * 4;
    int j0 = e0 & 7, ln = (e0 >> 3) & 63, kk = (e0 >> 9) & 31, bt = (e0 >> 14) & 7;
    int dir = e0 >> 17;
    const float* h0 = dir ? h_b : h_f;
    const float* sp = h0 + (bt * 16 + (ln & 15)) * H_ + kk * 32 + (ln >> 4) * 8 + j0;
    union { __bf16 b4[4]; uint2 u; } p;
#pragma unroll
    for (int q = 0; q < 4; ++q) p.b4[q] = (__bf16)sp[q];
    *(uint2*)(h0S + (size_t)e0) = p.u;
  }
}

// ---------------------------------------------------------------------------
__global__ void k_zero(float* __restrict__ out) {
  int i = blockIdx.x * 256 + threadIdx.x;
  ((float4*)out)[i] = float4{0.f, 0.f, 0.f, 0.f};
}

// ---------------------------------------------------------------------------
// k_gx: Gx[dir][v][j] = sum_k emb[v][k]*W[dir][k][j] + bias[j]   (fp32)
__global__ void k_gx(const float* __restrict__ emb, const float* __restrict__ Wf,
                     const float* __restrict__ Wb, const float* __restrict__ bf,
                     const float* __restrict__ bb, float* __restrict__ Gx) {
  __shared__ float ldsE[64 * 33];
  __shared__ float ldsW[32 * 129];
  int bid = blockIdx.x;
  int dir = bid >> 6, jt = (bid >> 1) & 31, vh = bid & 1;
  int jbase = jt * 128, vbase = vh * 64;
  const float* W    = dir ? Wb : Wf;
  const float* bias = dir ? bb : bf;
  int tid = threadIdx.x;
  int v0 = (tid & 3) * 16, j0 = (tid >> 2) * 2;
  float acc[16][2];
#pragma unroll
  for (int vv = 0; vv < 16; ++vv) { acc[vv][0] = 0.f; acc[vv][1] = 0.f; }
  for (int kc = 0; kc < 32; ++kc) {
    for (int idx = tid; idx < 2048; idx += 256) {
      int v = idx >> 5, k = idx & 31;
      ldsE[v * 33 + k] = emb[(vbase + v) * H_ + kc * 32 + k];
    }
    for (int idx = tid; idx < 4096; idx += 256) {
      int k = idx >> 7, j = idx & 127;
      ldsW[k * 129 + j] = W[(kc * 32 + k) * 4096 + jbase + j];
    }
    __syncthreads();
    for (int k = 0; k < 32; ++k) {
      float w0 = ldsW[k * 129 + j0], w1 = ldsW[k * 129 + j0 + 1];
#pragma unroll
      for (int vv = 0; vv < 16; ++vv) {
        float e = ldsE[(v0 + vv) * 33 + k];
        acc[vv][0] += e * w0;
        acc[vv][1] += e * w1;
      }
    }
    __syncthreads();
  }
#pragma unroll
  for (int vv = 0; vv < 16; ++vv)
#pragma unroll
    for (int jj = 0; jj < 2; ++jj)
      Gx[(dir * 128 + vbase + v0 + vv) * 4096 + jbase + j0 + jj] = acc[vv][jj] + bias[jbase + j0 + jj];
}

// ---------------------------------------------------------------------------
// k_ubpack: UB[dir][kk(32)][ctg(256)][lane(64)] uint4 of 8 bf16:
//   elem(lane,j) = W[dir][1024 + kk*32 + (lane>>4)*8 + j][ctg*16 + (lane&15)]
__global__ void k_ubpack(const float* __restrict__ Wf, const float* __restrict__ Wb,
                         uint4* __restrict__ UB) {
  __shared__ float ldsW[32 * 257];
  int bid = blockIdx.x;
  int dir = bid >> 5, kk = bid & 31;
  const float* W = dir ? Wb : Wf;
  int tid = threadIdx.x;
  for (int cc = 0; cc < 16; ++cc) {
    for (int idx = tid; idx < 32 * 256; idx += 256) {
      int kr = idx >> 8, cj = idx & 255;
      ldsW[kr * 257 + cj] = W[(1024 + kk * 32 + kr) * 4096 + cc * 256 + cj];
    }
    __syncthreads();
#pragma unroll
    for (int r = 0; r < 4; ++r) {
      int task = r * 256 + tid;
      int ctl = task >> 6, lane = task & 63;
      union { __bf16 b[8]; uint4 u; } p;
#pragma unroll
      for (int j = 0; j < 8; ++j)
        p.b[j] = (__bf16)ldsW[((lane >> 4) * 8 + j) * 257 + ctl * 16 + (lane & 15)];
      UB[((dir * 32 + kk) * 256 + cc * 16 + ctl) * 64 + lane] = p.u;
    }
    __syncthreads();
  }
}

// ---------------------------------------------------------------------------
// k_wobpack: WoB[kk(64)][nt(8)][lane(64)]: elem(lane,j) = W_out[kk*32+(lane>>4)*8+j][nt*16+(lane&15)]
__global__ void k_wobpack(const float* __restrict__ Wo, uint4* __restrict__ WoB) {
  int id = blockIdx.x * 256 + threadIdx.x;   // 32768 tasks
  int lane = id & 63, ntk = id >> 6;
  int nt = ntk & 7, kk = ntk >> 3;
  int k0 = kk * 32 + (lane >> 4) * 8;
  int n  = nt * 16 + (lane & 15);
  union { __bf16 b[8]; uint4 u; } p;
#pragma unroll
  for (int j = 0; j < 8; ++j) p.b[j] = (__bf16)Wo[(k0 + j) * V_ + n];
  WoB[id] = p.u;
}

// ---------------------------------------------------------------------------
// k_recur: persistent recurrence + fused projection. 256 blocks x 256 threads.
// block: g=bid&7 (dir=g>>2, bs=g&3), cg=bid>>3 (h-cols cg*32..+32; proj v-tile cg&7, store iff cg<8)
// ring hR per (dir,bs): [par(2)][bt2(2)][kk(32)][lane(64)][j(8)] bf16
__launch_bounds__(256, 1)
__global__ void k_recur(const int* __restrict__ xT, const uint4* __restrict__ UB,
                        const float* __restrict__ Gx, const unsigned short* __restrict__ h0S,
                        const float* __restrict__ c0f, const float* __restrict__ c0b,
                        const uint4* __restrict__ WoB, const float* __restrict__ b_out,
                        unsigned short* __restrict__ hR, unsigned* cnt,
                        float* __restrict__ out) {
  __shared__ __align__(16) unsigned char smem[65536];  // A-stage 64KB; gl & PP overlap it
  int tid = threadIdx.x;
  int wave = tid >> 6, lane = tid & 63;
  int quad = lane >> 4, l16 = lane & 15;
  int bid = blockIdx.x;
  int g = bid & 7, cg = bid >> 3;
  int dir = g >> 2, bs = g & 3;
  int hc0 = cg * 32;
  const float* c0 = dir ? c0b : c0f;
  unsigned short* ring = hR + (dir * 4 + bs) * 65536;  // 2 parities x 32768 shorts

  // ---- register-resident recurrent B strip: 64 frags = 256 VGPRs
  bf16x8 bfr[32][2];
#pragma unroll
  for (int kk = 0; kk < 32; ++kk)
#pragma unroll
    for (int ct = 0; ct < 2; ++ct) {
      int ctg = wave * 64 + cg * 2 + ct;
      bfr[kk][ct] = __builtin_bit_cast(bf16x8, UB[((dir * 32 + kk) * 256 + ctg) * 64 + lane]);
    }
  // ---- projection B frags: wave K-slice kk=wave*8..+8, v-tile nt=cg&7 (32 VGPRs)
  int nt = cg & 7;
  bf16x8 wob[8];
#pragma unroll
  for (int j = 0; j < 8; ++j)
    wob[j] = __builtin_bit_cast(bf16x8, WoB[((dir * 32 + wave * 8 + j) * 8 + nt) * 64 + lane]);
  bool do_proj = (cg < 8);

  // ---- pointwise mapping + persistent c state
  int prow = tid >> 3, pcolg = tid & 7;
  float creg[4];
#pragma unroll
  for (int q = 0; q < 4; ++q)
    creg[q] = c0[(bs * 32 + prow) * H_ + hc0 + pcolg * 4 + q];

  const uint4* aQ = (const uint4*)smem;
  float* gl = (float*)smem;                 // gate exchange [w][32][33] f32 (16.5KB)
  float* PP = (float*)(smem + 17408);       // proj partials [w][rt(2)][lane][4] f32 (8KB)

#pragma unroll 1
  for (int s = 0; s < S_; ++s) {
    int t_tok = dir ? (S_ - 1 - s) : s;

    // ---- stage h(prev) 32rows x 1024k (bf16 frag order) -> LDS 64KB
    {
      const unsigned short* src = (s == 0) ? (h0S + (dir * 8 + bs * 2) * 16384)
                                           : (ring + ((s - 1) & 1) * 32768);
#pragma unroll
      for (int it = 0; it < 16; ++it)
        gload_lds16(src + it * 2048 + tid * 8, smem + it * 4096 + wave * 1024);
    }

    // ---- C init from Gx gather (in flight with staging)
    f32x4 acc[2][2];
    {
      int tb = t_tok * 128 + bs * 32;
#pragma unroll
      for (int rt = 0; rt < 2; ++rt)
#pragma unroll
        for (int r = 0; r < 4; ++r) {
          int v = xT[tb + rt * 16 + quad * 4 + r];
          const float* gx = Gx + (dir * 128 + v) * 4096 + wave * 1024 + hc0;
          acc[rt][0][r] = gx[l16];
          acc[rt][1][r] = gx[16 + l16];
        }
    }
    __syncthreads();  // drains global_load_lds

    // ---- recurrence K loop: 32 x (2 ds_read_b128 + 4 MFMA), B in regs
#pragma unroll
    for (int kk = 0; kk < 32; ++kk) {
      bf16x8 a0 = __builtin_bit_cast(bf16x8, aQ[kk * 64 + lane]);
      bf16x8 a1 = __builtin_bit_cast(bf16x8, aQ[(32 + kk) * 64 + lane]);
      acc[0][0] = __builtin_amdgcn_mfma_f32_16x16x32_bf16(a0, bfr[kk][0], acc[0][0], 0, 0, 0);
      acc[0][1] = __builtin_amdgcn_mfma_f32_16x16x32_bf16(a0, bfr[kk][1], acc[0][1], 0, 0, 0);
      acc[1][0] = __builtin_amdgcn_mfma_f32_16x16x32_bf16(a1, bfr[kk][0], acc[1][0], 0, 0, 0);
      acc[1][1] = __builtin_amdgcn_mfma_f32_16x16x32_bf16(a1, bfr[kk][1], acc[1][1], 0, 0, 0);
    }

    // ---- fused projection of h(t_prev): same LDS A, wave's K-slice
    f32x4 pacc[2];
    if (do_proj && s > 0) {
      pacc[0] = f32x4{0.f, 0.f, 0.f, 0.f};
      pacc[1] = f32x4{0.f, 0.f, 0.f, 0.f};
#pragma unroll
      for (int j = 0; j < 8; ++j) {
        int kkl = wave * 8 + j;
        bf16x8 a0 = __builtin_bit_cast(bf16x8, aQ[kkl * 64 + lane]);
        bf16x8 a1 = __builtin_bit_cast(bf16x8, aQ[(32 + kkl) * 64 + lane]);
        pacc[0] = __builtin_amdgcn_mfma_f32_16x16x32_bf16(a0, wob[j], pacc[0], 0, 0, 0);
        pacc[1] = __builtin_amdgcn_mfma_f32_16x16x32_bf16(a1, wob[j], pacc[1], 0, 0, 0);
      }
    }
    __syncthreads();  // all aQ reads done before overwriting with gl/PP

    // ---- gate exchange (C layout: row=quad*4+r, col=l16) + proj partials
#pragma unroll
    for (int rt = 0; rt < 2; ++rt)
#pragma unroll
      for (int ct = 0; ct < 2; ++ct)
#pragma unroll
        for (int r = 0; r < 4; ++r)
          gl[wave * 1056 + (rt * 16 + quad * 4 + r) * 33 + ct * 16 + l16] = acc[rt][ct][r];
    if (do_proj && s > 0) {
#pragma unroll
      for (int rt = 0; rt < 2; ++rt)
#pragma unroll
        for (int r = 0; r < 4; ++r)
          PP[((wave * 2 + rt) * 64 + lane) * 4 + r] = pacc[rt][r];
    }
    __syncthreads();

    // ---- pointwise LSTM cell; h -> ring (bf16 frag order)
    {
      union { __bf16 b[4]; uint2 u; } hp;
      float hv[4];
#pragma unroll
      for (int q = 0; q < 4; ++q) {
        int col = pcolg * 4 + q;
        float ig = gl[0 * 1056 + prow * 33 + col];
        float fg = gl[1 * 1056 + prow * 33 + col];
        float og = gl[2 * 1056 + prow * 33 + col];
        float gg = gl[3 * 1056 + prow * 33 + col];
        float c = sigm(fg) * creg[q] + sigm(ig) * tanh_(gg);
        creg[q] = c;
        float h = sigm(og) * tanh_(c);
        hv[q] = h;
        hp.b[q] = (__bf16)h;
      }
      int lane16 = (prow & 15) | ((pcolg >> 1) << 4);
      int j0 = (pcolg & 1) * 4;
      unsigned short* dst = ring + (s & 1) * 32768 + (prow >> 4) * 16384 + cg * 512 + lane16 * 8 + j0;
      *(uint2*)dst = hp.u;
      if (s == S_ - 1) {  // final states: out = [logits, hf, hb, cf, cb]
        int b = bs * 32 + prow;
        float* hOut = out + 8388608 + dir * 131072;
        float* cOut = out + 8388608 + 262144 + dir * 131072;
#pragma unroll
        for (int q = 0; q < 4; ++q) {
          int col = pcolg * 4 + q;
          hOut[b * H_ + hc0 + col] = hv[q];
          cOut[b * H_ + hc0 + col] = creg[q];
        }
      }
    }
    // ---- proj reduce over 4 waves + atomicAdd into zeroed logits
    if (do_proj && s > 0) {
      int t_pp = dir ? (t_tok + 1) : (t_tok - 1);
#pragma unroll
      for (int h2 = 0; h2 < 2; ++h2) {
        int o = h2 * 256 + tid;
        int rt = o >> 8, ln = (o >> 2) & 63, r = o & 3;
        float v0 = PP[((0 + rt) * 64 + ln) * 4 + r] + PP[((2 + rt) * 64 + ln) * 4 + r]
                 + PP[((4 + rt) * 64 + ln) * 4 + r] + PP[((6 + rt) * 64 + ln) * 4 + r];
        int row = rt * 16 + ((ln >> 4) << 2) + r;
        int v = nt * 16 + (ln & 15);
        int b = bs * 32 + row;
        if (!dir) v0 += b_out[v];
        atomicAdd(&out[((size_t)b * S_ + t_pp) * V_ + v], v0);
      }
    }
    __syncthreads();

    // ---- 32-block group barrier: release arrive / relaxed poll / acquire fence
    if (tid == 0) {
      __hip_atomic_fetch_add(&cnt[g], 1u, __ATOMIC_RELEASE, __HIP_MEMORY_SCOPE_AGENT);
      unsigned tgt = 32u * (unsigned)(s + 1);
      while (__hip_atomic_load(&cnt[g], __ATOMIC_RELAXED, __HIP_MEMORY_SCOPE_AGENT) < tgt)
        __builtin_amdgcn_s_sleep(2);
    }
    __syncthreads();
    __threadfence();  // acquire: see other blocks' ring writes
  }

  // ---- epilogue: project the final h (t = S-1 fwd / 0 bwd)
  if (do_proj) {
    const unsigned short* src = ring + ((S_ - 1) & 1) * 32768;
#pragma unroll
    for (int it = 0; it < 16; ++it)
      gload_lds16(src + it * 2048 + tid * 8, smem + it * 4096 + wave * 1024);
    __syncthreads();
    f32x4 pacc[2];
    pacc[0] = f32x4{0.f, 0.f, 0.f, 0.f};
    pacc[1] = f32x4{0.f, 0.f, 0.f, 0.f};
#pragma unroll
    for (int j = 0; j < 8; ++j) {
      int kkl = wave * 8 + j;
      bf16x8 a0 = __builtin_bit_cast(bf16x8, aQ[kkl * 64 + lane]);
      bf16x8 a1 = __builtin_bit_cast(bf16x8, aQ[(32 + kkl) * 64 + lane]);
      pacc[0] = __builtin_amdgcn_mfma_f32_16x16x32_bf16(a0, wob[j], pacc[0], 0, 0, 0);
      pacc[1] = __builtin_amdgcn_mfma_f32_16x16x32_bf16(a1, wob[j], pacc[1], 0, 0, 0);
    }
    __syncthreads();
#pragma unroll
    for (int rt = 0; rt < 2; ++rt)
#pragma unroll
      for (int r = 0; r < 4; ++r)
        PP[((wave * 2 + rt) * 64 + lane) * 4 + r] = pacc[rt][r];
    __syncthreads();
    int t_pp = dir ? 0 : (S_ - 1);
#pragma unroll
    for (int h2 = 0; h2 < 2; ++h2) {
      int o = h2 * 256 + tid;
      int rt = o >> 8, ln = (o >> 2) & 63, r = o & 3;
      float v0 = PP[((0 + rt) * 64 + ln) * 4 + r] + PP[((2 + rt) * 64 + ln) * 4 + r]
               + PP[((4 + rt) * 64 + ln) * 4 + r] + PP[((6 + rt) * 64 + ln) * 4 + r];
      int row = rt * 16 + ((ln >> 4) << 2) + r;
      int v = nt * 16 + (ln & 15);
      int b = bs * 32 + row;
      if (!dir) v0 += b_out[v];
      atomicAdd(&out[((size_t)b * S_ + t_pp) * V_ + v], v0);
    }
  }
}

// ---------------------------------------------------------------------------
extern "C" void kernel_launch(void* const* d_in, const int* in_sizes, int n_in,
                              void* d_out, int out_size, void* d_ws, size_t ws_size,
                              hipStream_t stream) {
  (void)in_sizes; (void)n_in; (void)out_size; (void)ws_size;
  const int*   x   = (const int*)  d_in[0];
  const float* h_f = (const float*)d_in[1];
  const float* h_b = (const float*)d_in[2];
  const float* c_f = (const float*)d_in[3];
  const float* c_b = (const float*)d_in[4];
  const float* emb = (const float*)d_in[5];
  const float* W_f = (const float*)d_in[6];
  const float* b_f = (const float*)d_in[7];
  const float* W_b = (const float*)d_in[8];
  const float* b_b = (const float*)d_in[9];
  const float* W_o = (const float*)d_in[10];
  const float* b_o = (const float*)d_in[11];

  char* ws = (char*)d_ws;
  // ws layout (bytes): UB 16MB | Gx 4MB | WoB 512KB | xT 256KB | h0S 512KB | hR 1MB | cnt  (~23.3MB)
  uint4*  UB  = (uint4*)(ws);
  float*  Gx  = (float*)(ws + 16777216);
  uint4*  WoB = (uint4*)(ws + 20971520);
  int*    xT  = (int*)  (ws + 21495808);
  unsigned short* h0S = (unsigned short*)(ws + 21757952);
  unsigned short* hR  = (unsigned short*)(ws + 22282240);
  unsigned* cnt = (unsigned*)(ws + 23330816);
  float* out = (float*)d_out;

  k_init<<<512, 256, 0, stream>>>(x, h_f, h_b, xT, h0S, cnt);
  k_zero<<<8192, 256, 0, stream>>>(out);
  k_gx<<<128, 256, 0, stream>>>(emb, W_f, W_b, b_f, b_b, Gx);
  k_ubpack<<<64, 256, 0, stream>>>(W_f, W_b, UB);
  k_wobpack<<<128, 256, 0, stream>>>(W_o, WoB);
  k_recur<<<256, 256, 0, stream>>>(xT, UB, Gx, h0S, c_f, c_b, WoB, b_o, hR, cnt, out);
}

// Round 4
// 3415.899 us; speedup vs baseline: 4.0552x; 4.0552x over previous
//
#include <hip/hip_runtime.h>

// BLSTM: B=128, S=512, H=1024, VOCAB=128.
//  k_init    : transpose x -> xT[t][b], zero barrier counters, pack h0 -> A-frag layout
//  k_zero    : zero the logits region of out (projection accumulates via atomicAdd)
//  k_gx      : Gx[dir][v][4096] = emb[v] @ W[:1024] + b   (fp32, one-time)
//  k_ubpack  : U = W[1024:2048] -> bf16 MFMA B-frag layout (register-resident in k_recur)
//  k_wobpack : W_out -> bf16 B-frag layout
//  k_recur   : persistent 256-block kernel (1 block/CU); 512 steps; 32-block group
//              barrier/step. Cross-block h exchange uses DEVICE-COHERENT accesses
//              (stores sc0 sc1 write-through to IF$, loads sc0 sc1 bypass L1/L2) so
//              NO per-step buffer_wbl2/buffer_inv is needed (round-3's 26.8us/step
//              was L2 writeback-invalidate latency from RELEASE atomics+threadfence).

#define B_ 128
#define S_ 512
#define H_ 1024
#define V_ 128

typedef float  f32x4  __attribute__((ext_vector_type(4)));
typedef __bf16 bf16x8 __attribute__((ext_vector_type(8)));

__device__ inline float sigm(float x)  { return 1.0f / (1.0f + __expf(-x)); }
__device__ inline float tanh_(float x) { return 2.0f / (1.0f + __expf(-2.0f * x)) - 1.0f; }

typedef __attribute__((address_space(1))) void gvoid_t;
typedef __attribute__((address_space(3))) void lvoid_t;

// async global->LDS, 16B/lane; aux = CPol (SC0=1, SC1=16)
__device__ inline void gload_lds16_coh(const void* g, void* l) {
  __builtin_amdgcn_global_load_lds((gvoid_t*)g, (lvoid_t*)l, 16, 0, 0x11);
}
__device__ inline void gload_lds16(const void* g, void* l) {
  __builtin_amdgcn_global_load_lds((gvoid_t*)g, (lvoid_t*)l, 16, 0, 0);
}

// device-coherent 8B store: write-through to the device coherence point (IF$)
__device__ inline void store_u2_coh(void* p, uint2 v) {
  asm volatile("global_store_dwordx2 %0, %1, off sc0 sc1" :: "v"(p), "v"(v) : "memory");
}
// device-coherent 4B load (bypasses L1/L2)
__device__ inline unsigned load_u32_coh(const unsigned* p) {
  unsigned r;
  asm volatile("global_load_dword %0, %1, off sc0 sc1\n\ts_waitcnt vmcnt(0)"
               : "=v"(r) : "v"(p) : "memory");
  return r;
}

// ---------------------------------------------------------------------------
// k_init: xT + counters + h0 packed to A-frag layout (bf16)
// h0S: [dir][bt(8)][kk(32)][lane(64)][j(8)] bf16, elem = h[bt*16+(lane&15)][kk*32+(lane>>4)*8+j]
__global__ void k_init(const int* __restrict__ x, const float* __restrict__ h_f,
                       const float* __restrict__ h_b, int* __restrict__ xT,
                       unsigned short* __restrict__ h0S, unsigned* __restrict__ cnt) {
  int id = blockIdx.x * 256 + threadIdx.x;
  if (id < 65536) {
    int t = id >> 7, b = id & 127;
    xT[id] = x[b * S_ + t];
    if (id < 256) cnt[id] = 0u;   // padded counters: cnt[g*32]
  } else {
    int i2 = id - 65536;            // 0..65535, 4 elems each
    int e0 = i2 * 4;
    int j0 = e0 & 7, ln = (e0 >> 3) & 63, kk = (e0 >> 9) & 31, bt = (e0 >> 14) & 7;
    int dir = e0 >> 17;
    const float* h0 = dir ? h_b : h_f;
    const float* sp = h0 + (bt * 16 + (ln & 15)) * H_ + kk * 32 + (ln >> 4) * 8 + j0;
    union { __bf16 b4[4]; uint2 u; } p;
#pragma unroll
    for (int q = 0; q < 4; ++q) p.b4[q] = (__bf16)sp[q];
    *(uint2*)(h0S + (size_t)e0) = p.u;
  }
}

// ---------------------------------------------------------------------------
__global__ void k_zero(float* __restrict__ out) {
  int i = blockIdx.x * 256 + threadIdx.x;
  ((float4*)out)[i] = float4{0.f, 0.f, 0.f, 0.f};
}

// ---------------------------------------------------------------------------
// k_gx: Gx[dir][v][j] = sum_k emb[v][k]*W[dir][k][j] + bias[j]   (fp32)
__global__ void k_gx(const float* __restrict__ emb, const float* __restrict__ Wf,
                     const float* __restrict__ Wb, const float* __restrict__ bf,
                     const float* __restrict__ bb, float* __restrict__ Gx) {
  __shared__ float ldsE[64 * 33];
  __shared__ float ldsW[32 * 129];
  int bid = blockIdx.x;
  int dir = bid >> 6, jt = (bid >> 1) & 31, vh = bid & 1;
  int jbase = jt * 128, vbase = vh * 64;
  const float* W    = dir ? Wb : Wf;
  const float* bias = dir ? bb : bf;
  int tid = threadIdx.x;
  int v0 = (tid & 3) * 16, j0 = (tid >> 2) * 2;
  float acc[16][2];
#pragma unroll
  for (int vv = 0; vv < 16; ++vv) { acc[vv][0] = 0.f; acc[vv][1] = 0.f; }
  for (int kc = 0; kc < 32; ++kc) {
    for (int idx = tid; idx < 2048; idx += 256) {
      int v = idx >> 5, k = idx & 31;
      ldsE[v * 33 + k] = emb[(vbase + v) * H_ + kc * 32 + k];
    }
    for (int idx = tid; idx < 4096; idx += 256) {
      int k = idx >> 7, j = idx & 127;
      ldsW[k * 129 + j] = W[(kc * 32 + k) * 4096 + jbase + j];
    }
    __syncthreads();
    for (int k = 0; k < 32; ++k) {
      float w0 = ldsW[k * 129 + j0], w1 = ldsW[k * 129 + j0 + 1];
#pragma unroll
      for (int vv = 0; vv < 16; ++vv) {
        float e = ldsE[(v0 + vv) * 33 + k];
        acc[vv][0] += e * w0;
        acc[vv][1] += e * w1;
      }
    }
    __syncthreads();
  }
#pragma unroll
  for (int vv = 0; vv < 16; ++vv)
#pragma unroll
    for (int jj = 0; jj < 2; ++jj)
      Gx[(dir * 128 + vbase + v0 + vv) * 4096 + jbase + j0 + jj] = acc[vv][jj] + bias[jbase + j0 + jj];
}

// ---------------------------------------------------------------------------
// k_ubpack: UB[dir][kk(32)][ctg(256)][lane(64)] uint4 of 8 bf16:
//   elem(lane,j) = W[dir][1024 + kk*32 + (lane>>4)*8 + j][ctg*16 + (lane&15)]
__global__ void k_ubpack(const float* __restrict__ Wf, const float* __restrict__ Wb,
                         uint4* __restrict__ UB) {
  __shared__ float ldsW[32 * 257];
  int bid = blockIdx.x;
  int dir = bid >> 5, kk = bid & 31;
  const float* W = dir ? Wb : Wf;
  int tid = threadIdx.x;
  for (int cc = 0; cc < 16; ++cc) {
    for (int idx = tid; idx < 32 * 256; idx += 256) {
      int kr = idx >> 8, cj = idx & 255;
      ldsW[kr * 257 + cj] = W[(1024 + kk * 32 + kr) * 4096 + cc * 256 + cj];
    }
    __syncthreads();
#pragma unroll
    for (int r = 0; r < 4; ++r) {
      int task = r * 256 + tid;
      int ctl = task >> 6, lane = task & 63;
      union { __bf16 b[8]; uint4 u; } p;
#pragma unroll
      for (int j = 0; j < 8; ++j)
        p.b[j] = (__bf16)ldsW[((lane >> 4) * 8 + j) * 257 + ctl * 16 + (lane & 15)];
      UB[((dir * 32 + kk) * 256 + cc * 16 + ctl) * 64 + lane] = p.u;
    }
    __syncthreads();
  }
}

// ---------------------------------------------------------------------------
// k_wobpack: WoB[kk(64)][nt(8)][lane(64)]: elem(lane,j) = W_out[kk*32+(lane>>4)*8+j][nt*16+(lane&15)]
__global__ void k_wobpack(const float* __restrict__ Wo, uint4* __restrict__ WoB) {
  int id = blockIdx.x * 256 + threadIdx.x;   // 32768 tasks
  int lane = id & 63, ntk = id >> 6;
  int nt = ntk & 7, kk = ntk >> 3;
  int k0 = kk * 32 + (lane >> 4) * 8;
  int n  = nt * 16 + (lane & 15);
  union { __bf16 b[8]; uint4 u; } p;
#pragma unroll
  for (int j = 0; j < 8; ++j) p.b[j] = (__bf16)Wo[(k0 + j) * V_ + n];
  WoB[id] = p.u;
}

// ---------------------------------------------------------------------------
// k_recur: persistent recurrence + fused projection. 256 blocks x 256 threads.
// block: g=bid&7 (dir=g>>2, bs=g&3), cg=bid>>3 (h-cols cg*32..+32; proj v-tile cg&7, store iff cg<8)
// ring hR per (dir,bs): [par(2)][bt2(2)][kk(32)][lane(64)][j(8)] bf16
__launch_bounds__(256, 1)
__global__ void k_recur(const int* __restrict__ xT, const uint4* __restrict__ UB,
                        const float* __restrict__ Gx, const unsigned short* __restrict__ h0S,
                        const float* __restrict__ c0f, const float* __restrict__ c0b,
                        const uint4* __restrict__ WoB, const float* __restrict__ b_out,
                        unsigned short* __restrict__ hR, unsigned* cnt,
                        float* __restrict__ out) {
  __shared__ __align__(16) unsigned char smem[65536];  // A-stage 64KB; gl & PP overlap it
  int tid = threadIdx.x;
  int wave = tid >> 6, lane = tid & 63;
  int quad = lane >> 4, l16 = lane & 15;
  int bid = blockIdx.x;
  int g = bid & 7, cg = bid >> 3;
  int dir = g >> 2, bs = g & 3;
  int hc0 = cg * 32;
  const float* c0 = dir ? c0b : c0f;
  unsigned short* ring = hR + (dir * 4 + bs) * 65536;  // 2 parities x 32768 shorts
  unsigned* bar = cnt + g * 32;                        // 128B-padded counter

  // ---- register-resident recurrent B strip: 64 frags = 256 VGPRs
  bf16x8 bfr[32][2];
#pragma unroll
  for (int kk = 0; kk < 32; ++kk)
#pragma unroll
    for (int ct = 0; ct < 2; ++ct) {
      int ctg = wave * 64 + cg * 2 + ct;
      bfr[kk][ct] = __builtin_bit_cast(bf16x8, UB[((dir * 32 + kk) * 256 + ctg) * 64 + lane]);
    }
  // ---- projection B frags: wave K-slice kk=wave*8..+8, v-tile nt=cg&7 (32 VGPRs)
  int nt = cg & 7;
  bf16x8 wob[8];
#pragma unroll
  for (int j = 0; j < 8; ++j)
    wob[j] = __builtin_bit_cast(bf16x8, WoB[((dir * 32 + wave * 8 + j) * 8 + nt) * 64 + lane]);
  bool do_proj = (cg < 8);

  // ---- pointwise mapping + persistent c state
  int prow = tid >> 3, pcolg = tid & 7;
  float creg[4];
#pragma unroll
  for (int q = 0; q < 4; ++q)
    creg[q] = c0[(bs * 32 + prow) * H_ + hc0 + pcolg * 4 + q];

  const uint4* aQ = (const uint4*)smem;
  float* gl = (float*)smem;                 // gate exchange [w][32][33] f32 (16.5KB)
  float* PP = (float*)(smem + 17408);       // proj partials [w][rt(2)][lane][4] f32 (8KB)

#pragma unroll 1
  for (int s = 0; s < S_; ++s) {
    int t_tok = dir ? (S_ - 1 - s) : s;

    // ---- stage h(prev) 32rows x 1024k (bf16 frag order) -> LDS 64KB (coherent loads)
    {
      const unsigned short* src = (s == 0) ? (h0S + (dir * 8 + bs * 2) * 16384)
                                           : (ring + ((s - 1) & 1) * 32768);
#pragma unroll
      for (int it = 0; it < 16; ++it)
        gload_lds16_coh(src + it * 2048 + tid * 8, smem + it * 4096 + wave * 1024);
    }

    // ---- C init from Gx gather (in flight with staging; L2-cached, no inv anymore)
    f32x4 acc[2][2];
    {
      int tb = t_tok * 128 + bs * 32;
#pragma unroll
      for (int rt = 0; rt < 2; ++rt)
#pragma unroll
        for (int r = 0; r < 4; ++r) {
          int v = xT[tb + rt * 16 + quad * 4 + r];
          const float* gx = Gx + (dir * 128 + v) * 4096 + wave * 1024 + hc0;
          acc[rt][0][r] = gx[l16];
          acc[rt][1][r] = gx[16 + l16];
        }
    }
    __syncthreads();  // drains global_load_lds

    // ---- recurrence K loop: 32 x (2 ds_read_b128 + 4 MFMA), B in regs
#pragma unroll
    for (int kk = 0; kk < 32; ++kk) {
      bf16x8 a0 = __builtin_bit_cast(bf16x8, aQ[kk * 64 + lane]);
      bf16x8 a1 = __builtin_bit_cast(bf16x8, aQ[(32 + kk) * 64 + lane]);
      acc[0][0] = __builtin_amdgcn_mfma_f32_16x16x32_bf16(a0, bfr[kk][0], acc[0][0], 0, 0, 0);
      acc[0][1] = __builtin_amdgcn_mfma_f32_16x16x32_bf16(a0, bfr[kk][1], acc[0][1], 0, 0, 0);
      acc[1][0] = __builtin_amdgcn_mfma_f32_16x16x32_bf16(a1, bfr[kk][0], acc[1][0], 0, 0, 0);
      acc[1][1] = __builtin_amdgcn_mfma_f32_16x16x32_bf16(a1, bfr[kk][1], acc[1][1], 0, 0, 0);
    }

    // ---- fused projection of h(t_prev): same LDS A, wave's K-slice
    f32x4 pacc[2];
    if (do_proj && s > 0) {
      pacc[0] = f32x4{0.f, 0.f, 0.f, 0.f};
      pacc[1] = f32x4{0.f, 0.f, 0.f, 0.f};
#pragma unroll
      for (int j = 0; j < 8; ++j) {
        int kkl = wave * 8 + j;
        bf16x8 a0 = __builtin_bit_cast(bf16x8, aQ[kkl * 64 + lane]);
        bf16x8 a1 = __builtin_bit_cast(bf16x8, aQ[(32 + kkl) * 64 + lane]);
        pacc[0] = __builtin_amdgcn_mfma_f32_16x16x32_bf16(a0, wob[j], pacc[0], 0, 0, 0);
        pacc[1] = __builtin_amdgcn_mfma_f32_16x16x32_bf16(a1, wob[j], pacc[1], 0, 0, 0);
      }
    }
    __syncthreads();  // all aQ reads done before overwriting with gl/PP

    // ---- gate exchange (C layout: row=quad*4+r, col=l16) + proj partials
#pragma unroll
    for (int rt = 0; rt < 2; ++rt)
#pragma unroll
      for (int ct = 0; ct < 2; ++ct)
#pragma unroll
        for (int r = 0; r < 4; ++r)
          gl[wave * 1056 + (rt * 16 + quad * 4 + r) * 33 + ct * 16 + l16] = acc[rt][ct][r];
    if (do_proj && s > 0) {
#pragma unroll
      for (int rt = 0; rt < 2; ++rt)
#pragma unroll
        for (int r = 0; r < 4; ++r)
          PP[((wave * 2 + rt) * 64 + lane) * 4 + r] = pacc[rt][r];
    }
    __syncthreads();

    // ---- pointwise LSTM cell; h -> ring (bf16 frag order, write-through coherent)
    {
      union { __bf16 b[4]; uint2 u; } hp;
      float hv[4];
#pragma unroll
      for (int q = 0; q < 4; ++q) {
        int col = pcolg * 4 + q;
        float ig = gl[0 * 1056 + prow * 33 + col];
        float fg = gl[1 * 1056 + prow * 33 + col];
        float og = gl[2 * 1056 + prow * 33 + col];
        float gg = gl[3 * 1056 + prow * 33 + col];
        float c = sigm(fg) * creg[q] + sigm(ig) * tanh_(gg);
        creg[q] = c;
        float h = sigm(og) * tanh_(c);
        hv[q] = h;
        hp.b[q] = (__bf16)h;
      }
      int lane16 = (prow & 15) | ((pcolg >> 1) << 4);
      int j0 = (pcolg & 1) * 4;
      unsigned short* dst = ring + (s & 1) * 32768 + (prow >> 4) * 16384 + cg * 512 + lane16 * 8 + j0;
      store_u2_coh(dst, hp.u);
      if (s == S_ - 1) {  // final states: out = [logits, hf, hb, cf, cb]
        int b = bs * 32 + prow;
        float* hOut = out + 8388608 + dir * 131072;
        float* cOut = out + 8388608 + 262144 + dir * 131072;
#pragma unroll
        for (int q = 0; q < 4; ++q) {
          int col = pcolg * 4 + q;
          hOut[b * H_ + hc0 + col] = hv[q];
          cOut[b * H_ + hc0 + col] = creg[q];
        }
      }
    }
    // ---- proj reduce over 4 waves + atomicAdd into zeroed logits
    if (do_proj && s > 0) {
      int t_pp = dir ? (t_tok + 1) : (t_tok - 1);
#pragma unroll
      for (int h2 = 0; h2 < 2; ++h2) {
        int o = h2 * 256 + tid;
        int rt = o >> 8, ln = (o >> 2) & 63, r = o & 3;
        float v0 = PP[((0 + rt) * 64 + ln) * 4 + r] + PP[((2 + rt) * 64 + ln) * 4 + r]
                 + PP[((4 + rt) * 64 + ln) * 4 + r] + PP[((6 + rt) * 64 + ln) * 4 + r];
        int row = rt * 16 + ((ln >> 4) << 2) + r;
        int v = nt * 16 + (ln & 15);
        int b = bs * 32 + row;
        if (!dir) v0 += b_out[v];
        atomicAdd(&out[((size_t)b * S_ + t_pp) * V_ + v], v0);
      }
    }
    __syncthreads();  // vmcnt(0) drain: ring stores + atomics complete block-wide

    // ---- 32-block group barrier: RELAXED atomics only (no wbl2/inv), sc0sc1 poll
    if (tid == 0) {
      __hip_atomic_fetch_add(bar, 1u, __ATOMIC_RELAXED, __HIP_MEMORY_SCOPE_AGENT);
      unsigned tgt = 32u * (unsigned)(s + 1);
      while (load_u32_coh(bar) < tgt)
        __builtin_amdgcn_s_sleep(2);
    }
    __syncthreads();
  }

  // ---- epilogue: project the final h (t = S-1 fwd / 0 bwd)
  if (do_proj) {
    const unsigned short* src = ring + ((S_ - 1) & 1) * 32768;
#pragma unroll
    for (int it = 0; it < 16; ++it)
      gload_lds16_coh(src + it * 2048 + tid * 8, smem + it * 4096 + wave * 1024);
    __syncthreads();
    f32x4 pacc[2];
    pacc[0] = f32x4{0.f, 0.f, 0.f, 0.f};
    pacc[1] = f32x4{0.f, 0.f, 0.f, 0.f};
#pragma unroll
    for (int j = 0; j < 8; ++j) {
      int kkl = wave * 8 + j;
      bf16x8 a0 = __builtin_bit_cast(bf16x8, aQ[kkl * 64 + lane]);
      bf16x8 a1 = __builtin_bit_cast(bf16x8, aQ[(32 + kkl) * 64 + lane]);
      pacc[0] = __builtin_amdgcn_mfma_f32_16x16x32_bf16(a0, wob[j], pacc[0], 0, 0, 0);
      pacc[1] = __builtin_amdgcn_mfma_f32_16x16x32_bf16(a1, wob[j], pacc[1], 0, 0, 0);
    }
    __syncthreads();
#pragma unroll
    for (int rt = 0; rt < 2; ++rt)
#pragma unroll
      for (int r = 0; r < 4; ++r)
        PP[((wave * 2 + rt) * 64 + lane) * 4 + r] = pacc[rt][r];
    __syncthreads();
    int t_pp = dir ? 0 : (S_ - 1);
#pragma unroll
    for (int h2 = 0; h2 < 2; ++h2) {
      int o = h2 * 256 + tid;
      int rt = o >> 8, ln = (o >> 2) & 63, r = o & 3;
      float v0 = PP[((0 + rt) * 64 + ln) * 4 + r] + PP[((2 + rt) * 64 + ln) * 4 + r]
               + PP[((4 + rt) * 64 + ln) * 4 + r] + PP[((6 + rt) * 64 + ln) * 4 + r];
      int row = rt * 16 + ((ln >> 4) << 2) + r;
      int v = nt * 16 + (ln & 15);
      int b = bs * 32 + row;
      if (!dir) v0 += b_out[v];
      atomicAdd(&out[((size_t)b * S_ + t_pp) * V_ + v], v0);
    }
  }
}

// ---------------------------------------------------------------------------
extern "C" void kernel_launch(void* const* d_in, const int* in_sizes, int n_in,
                              void* d_out, int out_size, void* d_ws, size_t ws_size,
                              hipStream_t stream) {
  (void)in_sizes; (void)n_in; (void)out_size; (void)ws_size;
  const int*   x   = (const int*)  d_in[0];
  const float* h_f = (const float*)d_in[1];
  const float* h_b = (const float*)d_in[2];
  const float* c_f = (const float*)d_in[3];
  const float* c_b = (const float*)d_in[4];
  const float* emb = (const float*)d_in[5];
  const float* W_f = (const float*)d_in[6];
  const float* b_f = (const float*)d_in[7];
  const float* W_b = (const float*)d_in[8];
  const float* b_b = (const float*)d_in[9];
  const float* W_o = (const float*)d_in[10];
  const float* b_o = (const float*)d_in[11];

  char* ws = (char*)d_ws;
  // ws layout (bytes): UB 16MB | Gx 4MB | WoB 512KB | xT 256KB | h0S 512KB | hR 1MB | cnt 1KB
  uint4*  UB  = (uint4*)(ws);
  float*  Gx  = (float*)(ws + 16777216);
  uint4*  WoB = (uint4*)(ws + 20971520);
  int*    xT  = (int*)  (ws + 21495808);
  unsigned short* h0S = (unsigned short*)(ws + 21757952);
  unsigned short* hR  = (unsigned short*)(ws + 22282240);
  unsigned* cnt = (unsigned*)(ws + 23330816);
  float* out = (float*)d_out;

  k_init<<<512, 256, 0, stream>>>(x, h_f, h_b, xT, h0S, cnt);
  k_zero<<<8192, 256, 0, stream>>>(out);
  k_gx<<<128, 256, 0, stream>>>(emb, W_f, W_b, b_f, b_b, Gx);
  k_ubpack<<<64, 256, 0, stream>>>(W_f, W_b, UB);
  k_wobpack<<<128, 256, 0, stream>>>(W_o, WoB);
  k_recur<<<256, 256, 0, stream>>>(xT, UB, Gx, h0S, c_f, c_b, WoB, b_o, hR, cnt, out);
}